// Round 6
// baseline (233.278 us; speedup 1.0000x reference)
//
#include <hip/hip_runtime.h>

// GuidedFilterND: I (8,4,768,768) f32 guide, p (8,1,768,768) f32 input, r=8, eps=1e-4.
// Stage A: box-filter 19 product channels, per-pixel 4x4 SPD solve -> (As,b) float2 + sumI (ws)
// Stage B: box-filter (As,b); q = (f(As)*sumI + f(b)) / N
// Round 6: stage A identical to round 5 (proven 111 us, 0 conflicts).
//          Stage B rewritten as fully-parallel tiled box filter: 2 barriers per block
//          total (vs 2 per ROW before) — rounds 3/5 stage B (~110 us) was
//          latency-serialization-bound, not bandwidth/work-bound.

#define HH 768
#define WW 768
#define CC 4
#define BB 8
#define RR 8
#define EPSF 1.0e-4f

#define TA 128      // stage A threads per block
#define OUTA 112    // output columns per block (TA - 2*RR)
#define SHA 24      // stage A rows per stripe
#define NSTRIPE (HH / SHA)    // 32
#define NBAND 7               // ceil(768/112)

// stage B tile geometry
#define OTW 64      // output tile width
#define OTH 16      // output tile height
#define STW 80      // staged width  (OTW + 2*RR)
#define STH 32      // staged height (OTH + 2*RR)
#define TB  256     // stage B threads per block

__device__ __forceinline__ void loadpix(const float* __restrict__ Ib,
                                        const float* __restrict__ pb,
                                        int row, int gc, float pr[19]) {
  const int off = row * WW + gc;
  const int chs = HH * WW;
  float i0 = Ib[off];
  float i1 = Ib[chs + off];
  float i2 = Ib[2 * chs + off];
  float i3 = Ib[3 * chs + off];
  float pv = pb[off];
  pr[0] = i0; pr[1] = i1; pr[2] = i2; pr[3] = i3;
  pr[4] = pv;
  pr[5] = pv * i0; pr[6] = pv * i1; pr[7] = pv * i2; pr[8] = pv * i3;
  pr[9]  = i0 * i0; pr[10] = i0 * i1; pr[11] = i0 * i2; pr[12] = i0 * i3;
  pr[13] = i1 * i1; pr[14] = i1 * i2; pr[15] = i1 * i3;
  pr[16] = i2 * i2; pr[17] = i2 * i3;
  pr[18] = i3 * i3;
}

__global__ __launch_bounds__(TA) void gf_stageA(const float* __restrict__ I,
                                                const float* __restrict__ p,
                                                float2* __restrict__ AB,
                                                float* __restrict__ sumI_ws,
                                                int storeSum) {
  // thread-major, padded to 20 floats (80 B): b128 accesses, conflict-free
  __shared__ float v[TA][20];
  __shared__ float s4[TA][20];
  const int tid = threadIdx.x;
  const int band0 = (int)blockIdx.x * OUTA;
  const int r0 = (int)blockIdx.y * SHA;
  const int batch = (int)blockIdx.z;
  const int gc = band0 - RR + tid;            // column this thread's vertical sum covers
  const bool colok = (gc >= 0 && gc < WW);

  const float* Ib = I + (size_t)batch * CC * HH * WW;
  const float* pb = p + (size_t)batch * HH * WW;
  float* sIb = sumI_ws + (size_t)batch * HH * WW;

  float s[20];
#pragma unroll
  for (int k = 0; k < 20; ++k) s[k] = 0.0f;

  // warm-up: preload window of row (r0-1) = rows [r0-RR-1, r0+RR-1] clipped.
  if (colok) {
    int rlo = r0 - RR - 1; if (rlo < 0) rlo = 0;
    for (int row = rlo; row < r0 + RR; ++row) {
      float pr[19]; loadpix(Ib, pb, row, gc, pr);
#pragma unroll
      for (int k = 0; k < 19; ++k) s[k] += pr[k];
      // rows 0..7 are only ever touched by stripe 0's warm-up: store sumI here
      if (storeSum && r0 == 0)
        sIb[row * WW + gc] = pr[0] + pr[1] + pr[2] + pr[3];
    }
  }

  const int oc = band0 + tid;                 // output column for threads < OUTA
  const bool outok = (tid < OUTA) && (oc < WW);
  const int nw = min(oc + RR, WW - 1) - max(oc - RR, 0) + 1;

  for (int r = r0; r < r0 + SHA; ++r) {
    if (colok) {
      int rl = r + RR;
      if (rl < HH) {
        float pr[19]; loadpix(Ib, pb, rl, gc, pr);
#pragma unroll
        for (int k = 0; k < 19; ++k) s[k] += pr[k];
        if (storeSum)
          sIb[rl * WW + gc] = pr[0] + pr[1] + pr[2] + pr[3];
      }
      int rt = r - RR - 1;
      if (rt >= 0) {
        float pr[19]; loadpix(Ib, pb, rt, gc, pr);
#pragma unroll
        for (int k = 0; k < 19; ++k) s[k] -= pr[k];
      }
    }
    // publish vertical sums: 5 x b128 writes
    {
      float4* vp = (float4*)(&v[tid][0]);
      vp[0] = make_float4(s[0],  s[1],  s[2],  s[3]);
      vp[1] = make_float4(s[4],  s[5],  s[6],  s[7]);
      vp[2] = make_float4(s[8],  s[9],  s[10], s[11]);
      vp[3] = make_float4(s[12], s[13], s[14], s[15]);
      vp[4] = make_float4(s[16], s[17], s[18], 0.0f);
    }
    __syncthreads();
    float t4[20];
    if (tid < TA - 3) {
      const float* a1 = &v[tid + 1][0];
      const float* a2 = &v[tid + 2][0];
      const float* a3 = &v[tid + 3][0];
      float4* op = (float4*)(&s4[tid][0]);
#pragma unroll
      for (int j = 0; j < 5; ++j) {
        float4 xa = ((const float4*)a1)[j];
        float4 xb = ((const float4*)a2)[j];
        float4 xc = ((const float4*)a3)[j];
        float o0 = s[4*j + 0] + xa.x + xb.x + xc.x;
        float o1 = s[4*j + 1] + xa.y + xb.y + xc.y;
        float o2 = s[4*j + 2] + xa.z + xb.z + xc.z;
        float o3 = s[4*j + 3] + xa.w + xb.w + xc.w;
        op[j] = make_float4(o0, o1, o2, o3);
        t4[4*j + 0] = o0; t4[4*j + 1] = o1; t4[4*j + 2] = o2; t4[4*j + 3] = o3;
      }
    }
    __syncthreads();
    if (outok) {
      float h[20];
      const float* q4  = &s4[tid + 4][0];
      const float* q8  = &s4[tid + 8][0];
      const float* q12 = &s4[tid + 12][0];
      const float* q16 = &v[tid + 16][0];
#pragma unroll
      for (int j = 0; j < 5; ++j) {
        float4 a4 = ((const float4*)q4)[j];
        float4 b4 = ((const float4*)q8)[j];
        float4 c4 = ((const float4*)q12)[j];
        float4 d4 = ((const float4*)q16)[j];
        h[4*j + 0] = t4[4*j + 0] + a4.x + b4.x + c4.x + d4.x;
        h[4*j + 1] = t4[4*j + 1] + a4.y + b4.y + c4.y + d4.y;
        h[4*j + 2] = t4[4*j + 2] + a4.z + b4.z + c4.z + d4.z;
        h[4*j + 3] = t4[4*j + 3] + a4.w + b4.w + c4.w + d4.w;
      }
      const int nh = min(r + RR, HH - 1) - max(r - RR, 0) + 1;
      const float invN = 1.0f / (float)(nh * nw);
      float Im0 = h[0] * invN, Im1 = h[1] * invN, Im2 = h[2] * invN, Im3 = h[3] * invN;
      float pm = h[4] * invN;
      float ft0 = h[5] * invN - pm * Im0;
      float ft1 = h[6] * invN - pm * Im1;
      float ft2 = h[7] * invN - pm * Im2;
      float ft3 = h[8] * invN - pm * Im3;
      float m[4][4];
      m[0][0] = h[9]  * invN + EPSF;
      m[0][1] = h[10] * invN;
      m[0][2] = h[11] * invN;
      m[0][3] = h[12] * invN;
      m[1][1] = h[13] * invN + EPSF;
      m[1][2] = h[14] * invN;
      m[1][3] = h[15] * invN;
      m[2][2] = h[16] * invN + EPSF;
      m[2][3] = h[17] * invN;
      m[3][3] = h[18] * invN + EPSF;
      m[1][0] = m[0][1]; m[2][0] = m[0][2]; m[3][0] = m[0][3];
      m[2][1] = m[1][2]; m[3][1] = m[1][3]; m[3][2] = m[2][3];
      float y[4] = {1.0f, 1.0f, 1.0f, 1.0f};
#pragma unroll
      for (int k = 0; k < 4; ++k) {
        float piv = 1.0f / m[k][k];
#pragma unroll
        for (int j = 0; j < 4; ++j) m[k][j] *= piv;
        y[k] *= piv;
#pragma unroll
        for (int i = 0; i < 4; ++i) {
          if (i == k) continue;
          float f = m[i][k];
#pragma unroll
          for (int j = 0; j < 4; ++j) m[i][j] -= f * m[k][j];
          y[i] -= f * y[k];
        }
      }
      float Asum = ft0 * y[0] + ft1 * y[1] + ft2 * y[2] + ft3 * y[3];
      float bv = pm - Asum * (Im0 + Im1 + Im2 + Im3);
      AB[((size_t)batch * HH + r) * WW + oc] = make_float2(Asum, bv);
    }
    __syncthreads();
  }
}

// Stage B: fully-parallel tiled box filter. Output tile 64x16, staged 80x32 float2,
// colsum 80x16 float2. Exactly 2 barriers per block; no per-row serialization.
__global__ __launch_bounds__(TB) void gf_stageB(const float* __restrict__ I,
                                                const float2* __restrict__ AB,
                                                const float* __restrict__ sumI_ws,
                                                float* __restrict__ q, int useSum) {
  __shared__ float2 tile[STH][STW];   // 20.0 KB
  __shared__ float2 csum[OTH][STW];   // 10.0 KB
  const int t = threadIdx.x;
  const int bx = (int)blockIdx.x;     // 0..11
  const int by = (int)blockIdx.y;     // 0..47
  const int batch = (int)blockIdx.z;

  const float2* ABb = AB + (size_t)batch * HH * WW;
  const float* sIb = sumI_ws + (size_t)batch * HH * WW;
  const float* Ib = I + (size_t)batch * CC * HH * WW;

  const int gx0 = bx * OTW - RR;
  const int gy0 = by * OTH - RR;

  // phase 1: stage 80x32 window of AB (zero outside image)
#pragma unroll
  for (int k = 0; k < (STW * STH) / TB; ++k) {   // 10 iters
    const int idx = t + k * TB;
    const int x = idx % STW;
    const int y = idx / STW;
    const int gx = gx0 + x;
    const int gy = gy0 + y;
    const bool ok = (gx >= 0) && (gx < WW) && (gy >= 0) && (gy < HH);
    tile[y][x] = ok ? ABb[gy * WW + gx] : make_float2(0.0f, 0.0f);
  }
  __syncthreads();

  // phase 2: vertical 17-tap -> csum[cy][cx] for cy in [0,16), cx in [0,80)
#pragma unroll
  for (int k = 0; k < (STW * OTH) / TB; ++k) {   // 5 iters
    const int idx = t + k * TB;
    const int cx = idx % STW;
    const int cy = idx / STW;
    float sx = 0.0f, sy = 0.0f;
#pragma unroll
    for (int dy = 0; dy < 17; ++dy) {
      float2 u = tile[cy + dy][cx];
      sx += u.x; sy += u.y;
    }
    csum[cy][cx] = make_float2(sx, sy);
  }
  __syncthreads();

  // phase 3: horizontal 17-tap + epilogue; thread -> (tx, 4 rows)
  const int tx = t & 63;
  const int tg = t >> 6;                // 0..3
  const int oc = bx * OTW + tx;
  const int nw = min(oc + RR, WW - 1) - max(oc - RR, 0) + 1;
#pragma unroll
  for (int k = 0; k < 4; ++k) {
    const int rl = tg * 4 + k;          // 0..15
    const int ro = by * OTH + rl;
    float hx = 0.0f, hy = 0.0f;
#pragma unroll
    for (int dx = 0; dx < 17; ++dx) {
      float2 u = csum[rl][tx + dx];
      hx += u.x; hy += u.y;
    }
    const int nh = min(ro + RR, HH - 1) - max(ro - RR, 0) + 1;
    const float invN = 1.0f / (float)(nh * nw);
    float sumI;
    if (useSum) {
      sumI = sIb[ro * WW + oc];
    } else {
      const int off = ro * WW + oc;
      const int chs = HH * WW;
      sumI = Ib[off] + Ib[chs + off] + Ib[2 * chs + off] + Ib[3 * chs + off];
    }
    q[((size_t)batch * HH + ro) * WW + oc] = (hx * sumI + hy) * invN;
  }
}

extern "C" void kernel_launch(void* const* d_in, const int* in_sizes, int n_in,
                              void* d_out, int out_size, void* d_ws, size_t ws_size,
                              hipStream_t stream) {
  const float* I = (const float*)d_in[0];   // (8,4,768,768) f32
  const float* p = (const float*)d_in[1];   // (8,1,768,768) f32
  float* q = (float*)d_out;                 // (8,1,768,768) f32

  const size_t npix = (size_t)BB * HH * WW;
  float2* AB = (float2*)d_ws;                               // 37.75 MB
  float* sumI_ws = (float*)(AB + npix);                     // +18.87 MB
  const size_t need = npix * sizeof(float2) + npix * sizeof(float);
  const int useSum = (ws_size >= need) ? 1 : 0;             // constant across calls

  dim3 gridA(NBAND, NSTRIPE, BB);
  dim3 gridB(WW / OTW, HH / OTH, BB);       // 12 x 48 x 8 = 4608 blocks
  dim3 blockA(TA);
  dim3 blockB(TB);
  hipLaunchKernelGGL(gf_stageA, gridA, blockA, 0, stream, I, p, AB, sumI_ws, useSum);
  hipLaunchKernelGGL(gf_stageB, gridB, blockB, 0, stream, I, AB, sumI_ws, q, useSum);
}